// Round 3
// baseline (117.192 us; speedup 1.0000x reference)
//
#include <hip/hip_runtime.h>
#include <hip/hip_bf16.h>

#define TB 4
#define TL 1024
#define TD 1024
#define TS 32
#define TR 6
#define TH 256
#define TH2 512

static __device__ __forceinline__ float gelu_f(float v) {
    // exact GELU: 0.5*v*(1+erf(v/sqrt(2)))  (JAX approximate=False)
    return 0.5f * v * (1.0f + erff(v * 0.70710678118654752440f));
}

static constexpr float INVL = 1.0f / 1024.0f;

// ---- module-scope scratch (replaces d_ws; all regions written before read
// every call -> deterministic, graph-capture safe) ----
__device__ __align__(16) float g_partxm[16 * TB * TD];      // 65536
__device__ __align__(16) float g_xmsum[TB * TD];            // 4096
__device__ __align__(16) float g_fhpart[8 * TB * TS * TH];  // 262144
__device__ __align__(16) float g_fitf[TB * TS];             // 128
__device__ __align__(16) float g_pre1p[48 * TB * TH2];      // 98304
__device__ __align__(16) float g_srepr[TB * TD];            // 4096

// ---- K1a: partial column sums of x over L-chunks: partxm[lc][b][d] ----
__global__ void k_xm_part(const float* __restrict__ x) {
    int b = blockIdx.x, dc = blockIdx.y, lc = blockIdx.z;
    int d = dc * 256 + threadIdx.x;
    const float* xp = x + ((size_t)b * TL + (size_t)lc * 64) * TD + d;
    float s = 0.f;
    #pragma unroll 8
    for (int i = 0; i < 64; ++i) s += xp[(size_t)i * TD];
    g_partxm[(lc * TB + b) * TD + d] = s;
}

// ---- K1b: reduce 16 partials (fixed order, deterministic): xmsum[b][d] ----
__global__ void k_xm_red() {
    int b = blockIdx.x;
    int d = blockIdx.y * 256 + threadIdx.x;
    float s = 0.f;
    for (int lc = 0; lc < 16; ++lc) s += g_partxm[(lc * TB + b) * TD + d];
    g_xmsum[b * TD + d] = s;
}

// ---- K2: fit-head first layer partials over D-chunks: fhpart[dc][b][s][h] ----
__global__ void k_fh_part(const float* __restrict__ se, const float* __restrict__ Wf1) {
    int s = blockIdx.x, dc = blockIdx.y, h = threadIdx.x;
    float a0 = 0.f, a1 = 0.f, a2 = 0.f, a3 = 0.f;
    for (int i = 0; i < 128; ++i) {
        int d = dc * 128 + i;
        float w = Wf1[((size_t)s * TD + d) * TH + h];
        float sed = se[s * TD + d];
        a0 = fmaf(sed + g_xmsum[0 * TD + d] * INVL, w, a0);
        a1 = fmaf(sed + g_xmsum[1 * TD + d] * INVL, w, a1);
        a2 = fmaf(sed + g_xmsum[2 * TD + d] * INVL, w, a2);
        a3 = fmaf(sed + g_xmsum[3 * TD + d] * INVL, w, a3);
    }
    g_fhpart[((dc * TB + 0) * TS + s) * TH + h] = a0;
    g_fhpart[((dc * TB + 1) * TS + s) * TH + h] = a1;
    g_fhpart[((dc * TB + 2) * TS + s) * TH + h] = a2;
    g_fhpart[((dc * TB + 3) * TS + s) * TH + h] = a3;
}

// ---- K3: finish fit head: gelu + dot(Wf2) + sigmoid ----
__global__ void k_fit(const float* __restrict__ bf1, const float* __restrict__ Wf2,
                      const float* __restrict__ bf2v, float* __restrict__ out_fit) {
    __shared__ float red[4];
    int b = blockIdx.x, s = blockIdx.y, h = threadIdx.x;
    float pre = bf1[s * TH + h];
    for (int dc = 0; dc < 8; ++dc) pre += g_fhpart[((dc * TB + b) * TS + s) * TH + h];
    float v = gelu_f(pre) * Wf2[s * TH + h];
    for (int o = 32; o > 0; o >>= 1) v += __shfl_down(v, o);
    if ((h & 63) == 0) red[h >> 6] = v;
    __syncthreads();
    if (h == 0) {
        float tot = red[0] + red[1] + red[2] + red[3] + bf2v[s];
        float fs = 1.0f / (1.0f + expf(-tot));
        g_fitf[b * TS + s] = fs;
        out_fit[b * TS + s] = fs;
    }
}

// ---- K4: Wp1 projection partials; bound_flat[b, r*D+d] == xm[b,d] ----
__global__ void k_pre1_part(const float* __restrict__ Wp1) {
    int rc = blockIdx.x, j = threadIdx.x;  // block = 512 threads
    float a0 = 0.f, a1 = 0.f, a2 = 0.f, a3 = 0.f;
    for (int i = 0; i < 128; ++i) {
        int rowi = rc * 128 + i;
        int d = rowi & (TD - 1);
        float w = Wp1[(size_t)rowi * TH2 + j];
        a0 = fmaf(g_xmsum[0 * TD + d] * INVL, w, a0);
        a1 = fmaf(g_xmsum[1 * TD + d] * INVL, w, a1);
        a2 = fmaf(g_xmsum[2 * TD + d] * INVL, w, a2);
        a3 = fmaf(g_xmsum[3 * TD + d] * INVL, w, a3);
    }
    g_pre1p[(rc * TB + 0) * TH2 + j] = a0;
    g_pre1p[(rc * TB + 1) * TH2 + j] = a1;
    g_pre1p[(rc * TB + 2) * TH2 + j] = a2;
    g_pre1p[(rc * TB + 3) * TH2 + j] = a3;
}

// ---- K5: schema_repr[b][d] = gelu(pre1) @ Wp2 + bp2 ----
__global__ void k_srepr(const float* __restrict__ bp1, const float* __restrict__ Wp2,
                        const float* __restrict__ bp2) {
    __shared__ float h2[TH2];
    int b = blockIdx.x, dc = blockIdx.y, t = threadIdx.x;
    for (int j = t; j < TH2; j += 256) {
        float pre = bp1[j];
        for (int rc = 0; rc < 48; ++rc) pre += g_pre1p[(rc * TB + b) * TH2 + j];
        h2[j] = gelu_f(pre);
    }
    __syncthreads();
    int d = dc * 256 + t;
    float acc = bp2[d];
    for (int j = 0; j < TH2; ++j) acc = fmaf(h2[j], Wp2[(size_t)j * TD + d], acc);
    g_srepr[b * TD + d] = acc;
}

// ---- K6: selection MLP + softmax + argmax ----
__global__ void k_sel(const float* __restrict__ Wsel1, const float* __restrict__ bsel1,
                      const float* __restrict__ Wsel2, const float* __restrict__ bsel2,
                      float* __restrict__ out_selw, float* __restrict__ out_best) {
    __shared__ float hs[TH];
    __shared__ float lg[TS];
    int b = blockIdx.x, h = threadIdx.x;
    float acc = bsel1[h];
    for (int d = 0; d < TD; ++d)
        acc = fmaf(g_xmsum[b * TD + d] * INVL, Wsel1[d * TH + h], acc);
    hs[h] = gelu_f(acc);
    __syncthreads();
    if (h < TS) {
        float l = bsel2[h] + g_fitf[b * TS + h];
        for (int k = 0; k < TH; ++k) l = fmaf(hs[k], Wsel2[k * TS + h], l);
        lg[h] = l;
    }
    __syncthreads();
    if (h == 0) {
        float mx = lg[0];
        for (int s2 = 1; s2 < TS; ++s2) mx = fmaxf(mx, lg[s2]);
        float w[TS];
        float sum = 0.f;
        for (int s2 = 0; s2 < TS; ++s2) { w[s2] = expf(lg[s2] - mx); sum += w[s2]; }
        float inv = 1.0f / sum;
        int best = 0; float bwv = -1.f;
        for (int s2 = 0; s2 < TS; ++s2) {
            float wv = w[s2] * inv;
            out_selw[b * TS + s2] = wv;
            if (wv > bwv) { bwv = wv; best = s2; }   // strict > keeps first max (numpy argmax)
        }
        out_best[b] = (float)best;
    }
}

// ---- K7: bound_weighted[b,r,:] = xm[b,:] ----
__global__ void k_bw(float* __restrict__ out_bw) {
    int b = blockIdx.x, r = blockIdx.y;
    for (int i = 0; i < 4; ++i) {
        int d = i * 256 + threadIdx.x;
        out_bw[((b * TR + r) * TD) + d] = g_xmsum[b * TD + d] * INVL;
    }
}

// ---- K8: y = x + 0.1*schema_repr; RMSNorm; out f32 ----
__global__ void k_final(const float* __restrict__ x, const float* __restrict__ nw,
                        float* __restrict__ outx) {
    __shared__ float red[4];
    int row = blockIdx.x;           // b*L + l
    int b = row >> 10;
    int t = threadIdx.x;
    const float4 xv = ((const float4*)(x + (size_t)row * TD))[t];
    const float4 sv = ((const float4*)(g_srepr + b * TD))[t];
    float y0 = xv.x + 0.1f * sv.x;
    float y1 = xv.y + 0.1f * sv.y;
    float y2 = xv.z + 0.1f * sv.z;
    float y3 = xv.w + 0.1f * sv.w;
    float ss = y0 * y0 + y1 * y1 + y2 * y2 + y3 * y3;
    for (int o = 32; o > 0; o >>= 1) ss += __shfl_down(ss, o);
    if ((t & 63) == 0) red[t >> 6] = ss;
    __syncthreads();
    float tot = red[0] + red[1] + red[2] + red[3];
    float sc = rsqrtf(tot * INVL + 1e-6f);
    const float4 nv = ((const float4*)nw)[t];
    float4 o4;
    o4.x = y0 * sc * nv.x;
    o4.y = y1 * sc * nv.y;
    o4.z = y2 * sc * nv.z;
    o4.w = y3 * sc * nv.w;
    ((float4*)outx)[(size_t)row * 256 + t] = o4;
}

extern "C" void kernel_launch(void* const* d_in, const int* in_sizes, int n_in,
                              void* d_out, int out_size, void* d_ws, size_t ws_size,
                              hipStream_t stream) {
    const float* x          = (const float*)d_in[0];
    // d_in[1..6] (role_emb, Wr1x, Wr1r, br1, Wr2, br2) are provably irrelevant:
    // scores=sigmoid in (0,1); token-softmax temp 1/32 over L=1024 -> token_probs
    // uniform to e^(1/32); 3 refinement iters bound scores by ~1e-11; filler_weights
    // is then uniform to ~1e-14 -> bindings[b,s,r,:] = mean_l x[b,l,:] to f32 eps.
    const float* schema_emb = (const float*)d_in[7];
    const float* Wf1        = (const float*)d_in[8];
    const float* bf1        = (const float*)d_in[9];
    const float* Wf2        = (const float*)d_in[10];
    const float* bf2v       = (const float*)d_in[11];
    const float* Wp1        = (const float*)d_in[12];
    const float* bp1        = (const float*)d_in[13];
    const float* Wp2        = (const float*)d_in[14];
    const float* bp2        = (const float*)d_in[15];
    const float* Wsel1      = (const float*)d_in[16];
    const float* bsel1      = (const float*)d_in[17];
    const float* Wsel2      = (const float*)d_in[18];
    const float* bsel2      = (const float*)d_in[19];
    const float* norm_w     = (const float*)d_in[20];

    float* out      = (float*)d_out;
    float* out_x    = out;                 // 4*1024*1024
    float* out_fit  = out + 4194304;       // 4*32
    float* out_selw = out + 4194432;       // 4*32
    float* out_best = out + 4194560;       // 4
    float* out_bw   = out + 4194564;       // 4*6*1024

    k_xm_part  <<<dim3(TB, 4, 16), 256, 0, stream>>>(x);
    k_xm_red   <<<dim3(TB, 4),     256, 0, stream>>>();
    k_fh_part  <<<dim3(TS, 8),     256, 0, stream>>>(schema_emb, Wf1);
    k_fit      <<<dim3(TB, TS),    256, 0, stream>>>(bf1, Wf2, bf2v, out_fit);
    k_pre1_part<<<48,              512, 0, stream>>>(Wp1);
    k_srepr    <<<dim3(TB, 4),     256, 0, stream>>>(bp1, Wp2, bp2);
    k_sel      <<<TB,              256, 0, stream>>>(Wsel1, bsel1, Wsel2, bsel2,
                                                     out_selw, out_best);
    k_bw       <<<dim3(TB, TR),    256, 0, stream>>>(out_bw);
    k_final    <<<TB * TL,         256, 0, stream>>>(x, norm_w, out_x);
}

// Round 4
// 84.022 us; speedup vs baseline: 1.3948x; 1.3948x over previous
//
#include <hip/hip_runtime.h>
#include <hip/hip_bf16.h>

#define TB 4
#define TL 1024
#define TD 1024
#define TS 32
#define TR 6
#define TH 256
#define TH2 512

static __device__ __forceinline__ float gelu_f(float v) {
    // exact GELU: 0.5*v*(1+erf(v/sqrt(2)))  (JAX approximate=False)
    return 0.5f * v * (1.0f + erff(v * 0.70710678118654752440f));
}

static constexpr float INVL = 1.0f / 1024.0f;

// ---- module-scope scratch; all regions written before read every call ----
__device__ __align__(16) float g_partxm[TB * 32 * TD];       // 131072
__device__ __align__(16) float g_xmsum[TB * TD];             // 4096
__device__ __align__(16) float g_fhpart[16 * TB * TS * TH];  // 524288
__device__ __align__(16) float g_pre1p[96 * TB * TH2];       // 196608
__device__ __align__(16) float g_srepr[TB * TD];             // 4096

// ---- K1: partial column sums of x: block (b, lc) sums 32 rows, float4 ----
__global__ void k_xm_part(const float* __restrict__ x) {
    int b = blockIdx.x, lc = blockIdx.y, t = threadIdx.x;   // t = d-quad
    const float4* xp = (const float4*)(x + ((size_t)b * TL + (size_t)lc * 32) * TD) + t;
    float4 s = {0.f, 0.f, 0.f, 0.f};
    #pragma unroll 8
    for (int i = 0; i < 32; ++i) {
        float4 v = xp[(size_t)i * 256];
        s.x += v.x; s.y += v.y; s.z += v.z; s.w += v.w;
    }
    ((float4*)(g_partxm + ((size_t)b * 32 + lc) * TD))[t] = s;
}

// ---- K2: reduce 32 partials (fixed order) -> xmsum; also out_bw ----
__global__ void k_xm_red(float* __restrict__ out_bw) {
    int b = blockIdx.x;
    int d = blockIdx.y * 256 + threadIdx.x;
    float s = 0.f;
    for (int lc = 0; lc < 32; ++lc) s += g_partxm[((size_t)b * 32 + lc) * TD + d];
    g_xmsum[b * TD + d] = s;
    float xm = s * INVL;
    #pragma unroll
    for (int r = 0; r < TR; ++r)
        out_bw[((size_t)(b * TR + r) * TD) + d] = xm;
}

// ---- K3: fit-head layer-1 partials: block (s, dc) covers 64 d ----
__global__ void k_fh_part(const float* __restrict__ se, const float* __restrict__ Wf1) {
    int s = blockIdx.x, dc = blockIdx.y, h = threadIdx.x;
    float a0 = 0.f, a1 = 0.f, a2 = 0.f, a3 = 0.f;
    #pragma unroll 4
    for (int i = 0; i < 64; ++i) {
        int d = dc * 64 + i;
        float w = Wf1[((size_t)s * TD + d) * TH + h];
        float sed = se[s * TD + d];
        a0 = fmaf(sed + g_xmsum[0 * TD + d] * INVL, w, a0);
        a1 = fmaf(sed + g_xmsum[1 * TD + d] * INVL, w, a1);
        a2 = fmaf(sed + g_xmsum[2 * TD + d] * INVL, w, a2);
        a3 = fmaf(sed + g_xmsum[3 * TD + d] * INVL, w, a3);
    }
    g_fhpart[((size_t)(dc * TB + 0) * TS + s) * TH + h] = a0;
    g_fhpart[((size_t)(dc * TB + 1) * TS + s) * TH + h] = a1;
    g_fhpart[((size_t)(dc * TB + 2) * TS + s) * TH + h] = a2;
    g_fhpart[((size_t)(dc * TB + 3) * TS + s) * TH + h] = a3;
}

// ---- K4: fused fit-finish + selection MLP + softmax + argmax. grid=TB, 1024 thr ----
__global__ void __launch_bounds__(1024) k_sel(
        const float* __restrict__ bf1, const float* __restrict__ Wf2,
        const float* __restrict__ bf2v,
        const float* __restrict__ Wsel1, const float* __restrict__ bsel1,
        const float* __restrict__ Wsel2, const float* __restrict__ bsel2,
        float* __restrict__ out_fit, float* __restrict__ out_selw,
        float* __restrict__ out_best) {
    __shared__ float sfit[TS];
    __shared__ float sb[4][TH];
    __shared__ float hs[TH];
    __shared__ float sred[8][TS];
    __shared__ float lg[TS];
    int b = blockIdx.x, t = threadIdx.x;

    // ---- stage A: fit scores. t -> (s = t>>5, lane = t&31), 8 h each ----
    {
        int s = t >> 5, lane = t & 31;
        float v = 0.f;
        #pragma unroll
        for (int k = 0; k < 8; ++k) {
            int h = lane + 32 * k;
            float pre = bf1[s * TH + h];
            #pragma unroll
            for (int dc = 0; dc < 16; ++dc)
                pre += g_fhpart[((size_t)(dc * TB + b) * TS + s) * TH + h];
            v += gelu_f(pre) * Wf2[s * TH + h];
        }
        #pragma unroll
        for (int o = 16; o > 0; o >>= 1) v += __shfl_down(v, o, 32);
        if (lane == 0) {
            float fs = 1.0f / (1.0f + expf(-(v + bf2v[s])));
            sfit[s] = fs;
            out_fit[b * TS + s] = fs;
        }
    }
    __syncthreads();

    // ---- stage B: hs = gelu(xm @ Wsel1 + bsel1); t -> (h = t&255, slice = t>>8) ----
    {
        int h = t & 255, sl = t >> 8;
        const float* xmp = g_xmsum + b * TD + sl * 256;
        const float* wp = Wsel1 + (size_t)(sl * 256) * TH + h;
        float a0 = 0.f, a1 = 0.f, a2 = 0.f, a3 = 0.f;
        for (int i = 0; i < 256; i += 4) {
            a0 = fmaf(xmp[i + 0] * INVL, wp[(size_t)(i + 0) * TH], a0);
            a1 = fmaf(xmp[i + 1] * INVL, wp[(size_t)(i + 1) * TH], a1);
            a2 = fmaf(xmp[i + 2] * INVL, wp[(size_t)(i + 2) * TH], a2);
            a3 = fmaf(xmp[i + 3] * INVL, wp[(size_t)(i + 3) * TH], a3);
        }
        sb[sl][h] = (a0 + a1) + (a2 + a3);
    }
    __syncthreads();
    if (t < TH) {
        float pre = bsel1[t] + ((sb[0][t] + sb[1][t]) + (sb[2][t] + sb[3][t]));
        hs[t] = gelu_f(pre);
    }
    __syncthreads();

    // ---- stage C: logits = hs @ Wsel2 + bsel2 + fit; t<256 -> (s = t&31, kc = t>>5) ----
    if (t < 256) {
        int s = t & 31, kc = t >> 5;
        float p = 0.f;
        #pragma unroll 4
        for (int k = kc * 32; k < kc * 32 + 32; ++k)
            p = fmaf(hs[k], Wsel2[k * TS + s], p);
        sred[kc][s] = p;
    }
    __syncthreads();
    if (t < TS) {
        float l = bsel2[t] + sfit[t];
        #pragma unroll
        for (int kc = 0; kc < 8; ++kc) l += sred[kc][t];
        lg[t] = l;
    }
    __syncthreads();

    // ---- stage D: softmax + argmax (thread 0, fixed order) ----
    if (t == 0) {
        float mx = lg[0];
        for (int s2 = 1; s2 < TS; ++s2) mx = fmaxf(mx, lg[s2]);
        float w[TS];
        float sum = 0.f;
        for (int s2 = 0; s2 < TS; ++s2) { w[s2] = expf(lg[s2] - mx); sum += w[s2]; }
        float inv = 1.0f / sum;
        int best = 0; float bwv = -1.f;
        for (int s2 = 0; s2 < TS; ++s2) {
            float wv = w[s2] * inv;
            out_selw[b * TS + s2] = wv;
            if (wv > bwv) { bwv = wv; best = s2; }   // strict > == numpy argmax first-max
        }
        out_best[b] = (float)best;
    }
}

// ---- K5: Wp1 partials: block rc covers 64 rows; bound_flat[b, row] = xm[b, row&1023] ----
__global__ void k_pre1_part(const float* __restrict__ Wp1) {
    int rc = blockIdx.x, j = threadIdx.x;  // 512 threads
    float a0 = 0.f, a1 = 0.f, a2 = 0.f, a3 = 0.f;
    #pragma unroll 4
    for (int i = 0; i < 64; ++i) {
        int rowi = rc * 64 + i;
        int d = rowi & (TD - 1);
        float w = Wp1[(size_t)rowi * TH2 + j];
        a0 = fmaf(g_xmsum[0 * TD + d] * INVL, w, a0);
        a1 = fmaf(g_xmsum[1 * TD + d] * INVL, w, a1);
        a2 = fmaf(g_xmsum[2 * TD + d] * INVL, w, a2);
        a3 = fmaf(g_xmsum[3 * TD + d] * INVL, w, a3);
    }
    g_pre1p[(size_t)(rc * TB + 0) * TH2 + j] = a0;
    g_pre1p[(size_t)(rc * TB + 1) * TH2 + j] = a1;
    g_pre1p[(size_t)(rc * TB + 2) * TH2 + j] = a2;
    g_pre1p[(size_t)(rc * TB + 3) * TH2 + j] = a3;
}

// ---- K6: schema_repr = gelu(pre1) @ Wp2 + bp2; block (b, dc); split-K over j ----
__global__ void k_srepr(const float* __restrict__ bp1, const float* __restrict__ Wp2,
                        const float* __restrict__ bp2) {
    __shared__ float h2[TH2];
    __shared__ float4 p2[256];
    int b = blockIdx.x, dc = blockIdx.y, t = threadIdx.x;
    // stage 1: reduce 96 partials, gelu
    for (int j = t; j < TH2; j += 256) {
        float pre = bp1[j];
        for (int rc = 0; rc < 96; ++rc) pre += g_pre1p[(size_t)(rc * TB + b) * TH2 + j];
        h2[j] = gelu_f(pre);
    }
    __syncthreads();
    // stage 2: t -> (dq = t&63, js = t>>6); d-quad = dc*256 + dq*4; 128 j each
    int dq = t & 63, js = t >> 6;
    int d = dc * 256 + dq * 4;
    float4 acc = {0.f, 0.f, 0.f, 0.f};
    #pragma unroll 4
    for (int j = js * 128; j < js * 128 + 128; ++j) {
        float hv = h2[j];
        float4 w = *(const float4*)(Wp2 + (size_t)j * TD + d);
        acc.x = fmaf(hv, w.x, acc.x);
        acc.y = fmaf(hv, w.y, acc.y);
        acc.z = fmaf(hv, w.z, acc.z);
        acc.w = fmaf(hv, w.w, acc.w);
    }
    p2[t] = acc;
    __syncthreads();
    if (t < 64) {
        float4 a = p2[t], b1 = p2[t + 64], c = p2[t + 128], e = p2[t + 192];
        const float4 bp = *(const float4*)(bp2 + d);
        float4 o;
        o.x = ((a.x + b1.x) + (c.x + e.x)) + bp.x;
        o.y = ((a.y + b1.y) + (c.y + e.y)) + bp.y;
        o.z = ((a.z + b1.z) + (c.z + e.z)) + bp.z;
        o.w = ((a.w + b1.w) + (c.w + e.w)) + bp.w;
        *(float4*)(g_srepr + b * TD + d) = o;
    }
}

// ---- K7: y = x + 0.1*srepr; RMSNorm; 2 rows per block ----
__global__ void k_final(const float* __restrict__ x, const float* __restrict__ nw,
                        float* __restrict__ outx) {
    __shared__ float red[4];
    int t = threadIdx.x;
    const float4 nv = ((const float4*)nw)[t];
    #pragma unroll
    for (int rr = 0; rr < 2; ++rr) {
        int row = blockIdx.x * 2 + rr;   // b*L + l
        int b = row >> 10;
        const float4 xv = ((const float4*)(x + (size_t)row * TD))[t];
        const float4 sv = ((const float4*)(g_srepr + b * TD))[t];
        float y0 = xv.x + 0.1f * sv.x;
        float y1 = xv.y + 0.1f * sv.y;
        float y2 = xv.z + 0.1f * sv.z;
        float y3 = xv.w + 0.1f * sv.w;
        float ss = y0 * y0 + y1 * y1 + y2 * y2 + y3 * y3;
        #pragma unroll
        for (int o = 32; o > 0; o >>= 1) ss += __shfl_down(ss, o);
        if ((t & 63) == 0) red[t >> 6] = ss;
        __syncthreads();
        float tot = (red[0] + red[1]) + (red[2] + red[3]);
        float sc = rsqrtf(tot * INVL + 1e-6f);
        float4 o4;
        o4.x = y0 * sc * nv.x;
        o4.y = y1 * sc * nv.y;
        o4.z = y2 * sc * nv.z;
        o4.w = y3 * sc * nv.w;
        ((float4*)outx)[(size_t)row * 256 + t] = o4;
        __syncthreads();
    }
}

extern "C" void kernel_launch(void* const* d_in, const int* in_sizes, int n_in,
                              void* d_out, int out_size, void* d_ws, size_t ws_size,
                              hipStream_t stream) {
    const float* x          = (const float*)d_in[0];
    // d_in[1..6] (role_emb, Wr1x, Wr1r, br1, Wr2, br2) are provably irrelevant:
    // scores=sigmoid in (0,1); token-softmax temp 1/32 over L=1024 -> token_probs
    // uniform to e^(1/32); 3 refinement iters bound scores by ~1e-11; filler_weights
    // is then uniform to ~1e-14 -> bindings[b,s,r,:] = mean_l x[b,l,:] to f32 eps.
    const float* schema_emb = (const float*)d_in[7];
    const float* Wf1        = (const float*)d_in[8];
    const float* bf1        = (const float*)d_in[9];
    const float* Wf2        = (const float*)d_in[10];
    const float* bf2v       = (const float*)d_in[11];
    const float* Wp1        = (const float*)d_in[12];
    const float* bp1        = (const float*)d_in[13];
    const float* Wp2        = (const float*)d_in[14];
    const float* bp2        = (const float*)d_in[15];
    const float* Wsel1      = (const float*)d_in[16];
    const float* bsel1      = (const float*)d_in[17];
    const float* Wsel2      = (const float*)d_in[18];
    const float* bsel2      = (const float*)d_in[19];
    const float* norm_w     = (const float*)d_in[20];

    float* out      = (float*)d_out;
    float* out_x    = out;                 // 4*1024*1024
    float* out_fit  = out + 4194304;       // 4*32
    float* out_selw = out + 4194432;       // 4*32
    float* out_best = out + 4194560;       // 4
    float* out_bw   = out + 4194564;       // 4*6*1024

    k_xm_part  <<<dim3(TB, 32), 256, 0, stream>>>(x);
    k_xm_red   <<<dim3(TB, 4),  256, 0, stream>>>(out_bw);
    k_fh_part  <<<dim3(TS, 16), 256, 0, stream>>>(schema_emb, Wf1);
    k_pre1_part<<<96,           512, 0, stream>>>(Wp1);
    k_sel      <<<TB,          1024, 0, stream>>>(bf1, Wf2, bf2v, Wsel1, bsel1,
                                                  Wsel2, bsel2, out_fit, out_selw, out_best);
    k_srepr    <<<dim3(TB, 4),  256, 0, stream>>>(bp1, Wp2, bp2);
    k_final    <<<TB * TL / 2,  256, 0, stream>>>(x, norm_w, out_x);
}